// Round 9
// baseline (40.820 us; speedup 1.0000x reference)
//
#include <hip/hip_runtime.h>
#include <math.h>

// Problem constants
#define B 64
#define CIN 32
#define COUT 32
#define E 16
#define TOPK 4

typedef __attribute__((ext_vector_type(8))) short short8;
typedef __attribute__((ext_vector_type(4))) float f32x4;

// round-to-nearest-even f32 -> bf16 bits
__device__ __forceinline__ unsigned short f2bf(float f) {
    unsigned int u = __float_as_uint(f);
    u += 0x7fffu + ((u >> 16) & 1u);
    return (unsigned short)(u >> 16);
}

// XCD swizzle for 1024-block grids: sample b -> XCD (b>>3) in all kernels.
__device__ __forceinline__ int swz1024(int o) { return (o & 7) * 128 + (o >> 3); }

// ---------------------------------------------------------------------------
// Kernel 1: band sums of x (for the gating mean).  grid B*16 swizzled,
//   block 256 = 4 waves.  Wave-coalesced float4 reads, butterfly reduce.
// ---------------------------------------------------------------------------
__global__ void __launch_bounds__(256)
bandsum_kernel(const float* __restrict__ x, float* __restrict__ bandsum) {
    int blk = swz1024(blockIdx.x);
    int b = blk >> 4, band = blk & 15, h0 = band << 2;
    int t = threadIdx.x, wave = t >> 6, l = t & 63;
    const float4* x4 = reinterpret_cast<const float4*>(x);

    float racc[8];
    #pragma unroll
    for (int k = 0; k < 8; k++) {
        int c = k * 4 + wave;
        float4 v = x4[(((size_t)(b * 32 + c) * 64 + h0 + (l >> 4)) << 4) + (l & 15)];
        racc[k] = (v.x + v.y) + (v.z + v.w);
    }
    #pragma unroll
    for (int off = 1; off < 64; off <<= 1)
        #pragma unroll
        for (int k = 0; k < 8; k++) racc[k] += __shfl_xor(racc[k], off, 64);
    if (l == 0) {
        #pragma unroll
        for (int k = 0; k < 8; k++)
            bandsum[((size_t)b * 16 + band) * 32 + k * 4 + wave] = racc[k];
    }
}

// ---------------------------------------------------------------------------
// Kernel 2 (fused): gating + weight combine into LDS + conflict-free
//   two-stage NCHW->grouped-NHWC bf16 transpose + MFMA conv.
//   grid = B*16 swizzled, block 256 = 4 waves.
//   sx layout [cg][rr][wp][8]: pixel stride 16B -> dense lane-consecutive
//   ds ops on BOTH write and read sides (no c-fastest 64B pixel stride).
// ---------------------------------------------------------------------------
__global__ void __launch_bounds__(256)
conv_fused(const float* __restrict__ x,
           const float* __restrict__ bandsum,
           const float* __restrict__ noise,
           const float* __restrict__ w_gate,
           const float* __restrict__ w_noise,
           const float* __restrict__ expert_w,
           const float* __restrict__ expert_b,
           float* __restrict__ probw,
           float* __restrict__ gimpw,
           float* __restrict__ y) {
    int blk = swz1024(blockIdx.x);
    int b = blk >> 4, band = blk & 15, h0 = band << 2;
    int t = threadIdx.x, wave = t >> 6, l = t & 63;
    int ln = l & 15, lk = l >> 4;

    __shared__ float tmp[32 * 204];               // [c][rrl(3)][68] f32, 26112 B
    __shared__ unsigned short sx[4 * 6 * 66 * 8]; // [cg][rr][wp][8] bf16, 25344 B
    __shared__ unsigned short cw[9 * 1024];       // combined weights, 18432 B
    __shared__ float gx[32], s_bias[32];
    __shared__ float s_clean[E], s_std[E], s_noisy[E], s_lg[E];
    __shared__ float s_tv[TOPK + 1], s_g[TOPK];
    __shared__ int   s_gi[TOPK];

    // ---- gating: gate_x from bandsum ----
    if (t < 32) {
        const float* bp = bandsum + (size_t)b * 16 * 32 + t;
        float s = 0.f;
        #pragma unroll
        for (int j = 0; j < 16; j++) s += bp[j * 32];
        gx[t] = s * (1.f / 4096.f);
    }
    __syncthreads();
    if (t < E) {
        float s1 = 0.f, s2 = 0.f;
        #pragma unroll
        for (int c = 0; c < CIN; c++) {
            float g = gx[c];
            s1 += g * w_gate[c * E + t];
            s2 += g * w_noise[c * E + t];
        }
        float sp = fmaxf(s2, 0.f) + log1pf(expf(-fabsf(s2)));
        s_clean[t] = s1;
        s_std[t]   = sp + 0.01f;
        s_noisy[t] = s1 + noise[b * E + t] * (sp + 0.01f);
    }
    __syncthreads();
    if (t < E) {
        float m = s_noisy[0];
        #pragma unroll
        for (int e = 1; e < E; e++) m = fmaxf(m, s_noisy[e]);
        float den = 0.f;
        #pragma unroll
        for (int e = 0; e < E; e++) den += expf(s_noisy[e] - m);
        s_lg[t] = expf(s_noisy[t] - m) / den;
    }
    __syncthreads();
    // rank-based stable top-k
    if (t < E) {
        float v = s_lg[t]; int rank = 0;
        #pragma unroll
        for (int j = 0; j < E; j++) {
            float u = s_lg[j];
            rank += (u > v) || (u == v && j < t);
        }
        if (rank <= TOPK) s_tv[rank] = v;
        if (rank <  TOPK) s_gi[rank] = t;
    }
    __syncthreads();
    if (t < TOPK) {
        float s4 = s_tv[0] + s_tv[1] + s_tv[2] + s_tv[3] + 1e-6f;
        s_g[t] = s_tv[t] / s4;
    }
    __syncthreads();

    // loss inputs, once per sample (band 0 blocks)
    if (band == 0 && t < E) {
        float s4 = s_tv[0] + s_tv[1] + s_tv[2] + s_tv[3] + 1e-6f;
        float v = s_lg[t]; int rank = 0;
        #pragma unroll
        for (int j = 0; j < E; j++) {
            float u = s_lg[j];
            rank += (u > v) || (u == v && j < t);
        }
        gimpw[b * E + t] = (rank < TOPK) ? v / s4 : 0.f;
        const float INV_SQRT2 = 0.70710678118654752f;
        float thr_in = s_tv[TOPK], thr_out = s_tv[TOPK - 1];
        float thr = (s_noisy[t] > thr_in) ? thr_in : thr_out;
        float z = (s_clean[t] - thr) / s_std[t];
        probw[b * E + t] = 0.5f * (1.f + erff(z * INV_SQRT2));
    }

    // ---- weight combine into LDS ----
    {
        const float* e0 = expert_w + s_gi[0] * 9216;
        const float* e1 = expert_w + s_gi[1] * 9216;
        const float* e2 = expert_w + s_gi[2] * 9216;
        const float* e3 = expert_w + s_gi[3] * 9216;
        float g0 = s_g[0], g1 = s_g[1], g2 = s_g[2], g3 = s_g[3];
        #pragma unroll
        for (int k = 0; k < 36; k++) {
            int o = k * 256 + t;            // expert-native order (coalesced)
            int cc = o / 9, tap = o - cc * 9;
            float s = g0 * e0[o] + g1 * e1[o] + g2 * e2[o] + g3 * e3[o];
            cw[tap * 1024 + cc] = f2bf(s);
        }
        if (t < 32)
            s_bias[t] = s_g[0] * expert_b[s_gi[0] * 32 + t] + s_g[1] * expert_b[s_gi[1] * 32 + t]
                      + s_g[2] * expert_b[s_gi[2] * 32 + t] + s_g[3] * expert_b[s_gi[3] * 32 + t];
    }

    // ---- slab transpose: two 3-row passes through f32 bounce buffer ----
    const float4* x4 = reinterpret_cast<const float4*>(x);
    #pragma unroll
    for (int p = 0; p < 2; p++) {
        __syncthreads();   // tmp free (covers cw-combine on p=0, phase B on p=1)
        // phase A: coalesced global float4 -> dense LDS float4 (NCHW)
        #pragma unroll
        for (int k = 0; k < 6; k++) {
            int e = k * 256 + t;           // 32c x 3rrl x 16w4
            int w4 = e & 15, c = (e >> 4) & 31, rrl = e >> 9;
            int gr = h0 - 1 + p * 3 + rrl;
            float4 v = {0.f, 0.f, 0.f, 0.f};
            if ((unsigned)gr < 64u)
                v = x4[(((size_t)(b * 32 + c) * 64 + gr) << 4) + w4];
            *reinterpret_cast<float4*>(&tmp[c * 204 + rrl * 68 + w4 * 4]) = v;
        }
        __syncthreads();
        // phase B: 8 dense scalar reads per lane, convert, one short8 store
        #pragma unroll
        for (int k = 0; k < 4; k++) {
            int e = k * 256 + t;           // (cg*3 + rrl)*66 + wp, 792 total
            if (e < 792) {
                int wp = e % 66, q2 = e / 66;
                int rrl = q2 % 3, cg = q2 / 3;
                short8 ov;
                if (wp >= 1 && wp <= 64) {
                    #pragma unroll
                    for (int j = 0; j < 8; j++)
                        ov[j] = (short)f2bf(tmp[(cg * 8 + j) * 204 + rrl * 68 + (wp - 1)]);
                } else {
                    #pragma unroll
                    for (int j = 0; j < 8; j++) ov[j] = 0;
                }
                *reinterpret_cast<short8*>(
                    &sx[((cg * 6 + (p * 3 + rrl)) * 66 + wp) * 8]) = ov;
            }
        }
    }
    __syncthreads();

    // ---- MFMA conv: 9 shifted GEMMs, K=32 per mfma_f32_16x16x32_bf16 ----
    short8 afrag[2][9];
    #pragma unroll
    for (int tap = 0; tap < 9; tap++)
        #pragma unroll
        for (int ch = 0; ch < 2; ch++)
            afrag[ch][tap] = *reinterpret_cast<const short8*>(
                &cw[tap * 1024 + (ch * 16 + ln) * 32 + lk * 8]);

    float bias0[4], bias1[4];
    #pragma unroll
    for (int r = 0; r < 4; r++) {
        bias0[r] = s_bias[lk * 4 + r];
        bias1[r] = s_bias[16 + lk * 4 + r];
    }

    int h = h0 + wave;
    for (int tile = 0; tile < 4; tile++) {
        int w0 = tile * 16;
        f32x4 acc0 = {0.f, 0.f, 0.f, 0.f};
        f32x4 acc1 = {0.f, 0.f, 0.f, 0.f};
        #pragma unroll
        for (int kh = 0; kh < 3; kh++) {
            int rr = wave + kh;
            #pragma unroll
            for (int kw = 0; kw < 3; kw++) {
                int wp = w0 + ln + kw;
                short8 bfrag = *reinterpret_cast<const short8*>(
                    &sx[((lk * 6 + rr) * 66 + wp) * 8]);
                acc0 = __builtin_amdgcn_mfma_f32_16x16x32_bf16(afrag[0][kh * 3 + kw], bfrag, acc0, 0, 0, 0);
                acc1 = __builtin_amdgcn_mfma_f32_16x16x32_bf16(afrag[1][kh * 3 + kw], bfrag, acc1, 0, 0, 0);
            }
        }
        #pragma unroll
        for (int r = 0; r < 4; r++) {
            y[((size_t)(b * COUT + lk * 4 + r) * 64 + h) * 64 + w0 + ln]      = acc0[r] + bias0[r];
            y[((size_t)(b * COUT + 16 + lk * 4 + r) * 64 + h) * 64 + w0 + ln] = acc1[r] + bias1[r];
        }
    }
}

// ---------------------------------------------------------------------------
// Kernel 3: loss from per-sample prob / gate rows.  1 block, 64 threads.
// ---------------------------------------------------------------------------
__global__ void loss_kernel(const float* __restrict__ probw,
                            const float* __restrict__ gimpw,
                            float* __restrict__ loss_out) {
    __shared__ float s_lv[32];
    int t = threadIdx.x;
    if (t < 32) {
        const float* src = (t < 16) ? gimpw : probw;
        int e = t & 15;
        float s = 0.f;
        for (int bb = 0; bb < B; bb++) s += src[bb * E + e];
        s_lv[t] = s;
    }
    __syncthreads();
    if (t == 0) {
        float loss = 0.f;
        for (int pass = 0; pass < 2; pass++) {
            const float* v = s_lv + pass * 16;
            float mean = 0.f;
            for (int e = 0; e < E; e++) mean += v[e];
            mean *= (1.f / E);
            float var = 0.f;
            for (int e = 0; e < E; e++) { float d = v[e] - mean; var += d * d; }
            var *= (1.f / (E - 1));
            loss += var / (mean * mean + 1e-10f);
        }
        loss_out[0] = loss * 0.01f;
    }
}

// ---------------------------------------------------------------------------
extern "C" void kernel_launch(void* const* d_in, const int* in_sizes, int n_in,
                              void* d_out, int out_size, void* d_ws, size_t ws_size,
                              hipStream_t stream) {
    const float* x        = (const float*)d_in[0];
    const float* noise    = (const float*)d_in[1];
    const float* w_gate   = (const float*)d_in[2];
    const float* w_noise  = (const float*)d_in[3];
    const float* expert_w = (const float*)d_in[4];
    const float* expert_b = (const float*)d_in[5];

    float* y    = (float*)d_out;
    float* loss = y + (size_t)B * COUT * 64 * 64;

    char* ws = (char*)d_ws;
    float* bands  = (float*)(ws);            // 131,072 B
    float* probw  = (float*)(ws + 131072);   //   4,096 B
    float* gimpw  = (float*)(ws + 135168);   //   4,096 B

    bandsum_kernel<<<B * 16, 256, 0, stream>>>(x, bands);
    conv_fused<<<B * 16, 256, 0, stream>>>(x, bands, noise, w_gate, w_noise,
                                           expert_w, expert_b, probw, gimpw, y);
    loss_kernel<<<1, 64, 0, stream>>>(probw, gimpw, loss);
}

// Round 10
// 32.878 us; speedup vs baseline: 1.2416x; 1.2416x over previous
//
#include <hip/hip_runtime.h>
#include <math.h>

// Problem constants
#define B 64
#define CIN 32
#define COUT 32
#define E 16
#define TOPK 4

typedef __attribute__((ext_vector_type(8))) short short8;
typedef __attribute__((ext_vector_type(4))) float f32x4;

// round-to-nearest-even f32 -> bf16 bits
__device__ __forceinline__ unsigned short f2bf(float f) {
    unsigned int u = __float_as_uint(f);
    u += 0x7fffu + ((u >> 16) & 1u);
    return (unsigned short)(u >> 16);
}

// XCD swizzles: sample b -> XCD (b>>3) in every kernel, so x rows / cwb of a
// sample stay in one XCD's L2 across the whole pipeline.
__device__ __forceinline__ int swz1024(int o) { return (o & 7) * 128 + (o >> 3); }
__device__ __forceinline__ int swz256(int o)  { return (o & 7) * 32  + (o >> 3); }

// LDS channel swizzle for the c-fastest slab (R8-measured layout)
__device__ __forceinline__ int cswz(int wp, int c) {
    return c ^ (((wp >> 2) & 3) << 3);
}

// ---------------------------------------------------------------------------
// Kernel 1: band sums of x (for the gating mean).  grid B*16 swizzled,
//   block 256 = 4 waves.  Wave-coalesced float4 reads, butterfly reduce.
// ---------------------------------------------------------------------------
__global__ void __launch_bounds__(256)
bandsum_kernel(const float* __restrict__ x, float* __restrict__ bandsum) {
    int blk = swz1024(blockIdx.x);
    int b = blk >> 4, band = blk & 15, h0 = band << 2;
    int t = threadIdx.x, wave = t >> 6, l = t & 63;
    const float4* x4 = reinterpret_cast<const float4*>(x);

    float racc[8];
    #pragma unroll
    for (int k = 0; k < 8; k++) {
        int c = k * 4 + wave;
        float4 v = x4[(((size_t)(b * 32 + c) * 64 + h0 + (l >> 4)) << 4) + (l & 15)];
        racc[k] = (v.x + v.y) + (v.z + v.w);
    }
    #pragma unroll
    for (int off = 1; off < 64; off <<= 1)
        #pragma unroll
        for (int k = 0; k < 8; k++) racc[k] += __shfl_xor(racc[k], off, 64);
    if (l == 0) {
        #pragma unroll
        for (int k = 0; k < 8; k++)
            bandsum[((size_t)b * 16 + band) * 32 + k * 4 + wave] = racc[k];
    }
}

// ---------------------------------------------------------------------------
// Kernel 2: gating + combined weights -> global cwb (bf16 [b][tap][cout][cin])
//   grid = 256 (64 samples x 4 quarters) XCD-matched, block 256.
//   Output-major loop: dense 2B-consecutive cwb stores; stride-9 expert_w
//   gathers from L2/L3-hot 2.3 MB.  q==0 also writes cbias/probw/gimpw.
// ---------------------------------------------------------------------------
__global__ void __launch_bounds__(256)
gate_combine(const float* __restrict__ bandsum,
             const float* __restrict__ noise,
             const float* __restrict__ w_gate,
             const float* __restrict__ w_noise,
             const float* __restrict__ expert_w,
             const float* __restrict__ expert_b,
             unsigned short* __restrict__ cwb,
             float* __restrict__ cbias,
             float* __restrict__ probw,
             float* __restrict__ gimpw) {
    int blk = swz256(blockIdx.x);
    int b = blk >> 2, q = blk & 3;
    int t = threadIdx.x;

    __shared__ float gx[32];
    __shared__ float s_clean[E], s_std[E], s_noisy[E], s_lg[E];
    __shared__ float s_tv[TOPK + 1], s_g[TOPK];
    __shared__ int   s_gi[TOPK];

    if (t < 32) {
        const float* bp = bandsum + (size_t)b * 16 * 32 + t;
        float s = 0.f;
        #pragma unroll
        for (int j = 0; j < 16; j++) s += bp[j * 32];
        gx[t] = s * (1.f / 4096.f);
    }
    __syncthreads();
    if (t < E) {
        float s1 = 0.f, s2 = 0.f;
        #pragma unroll
        for (int c = 0; c < CIN; c++) {
            float g = gx[c];
            s1 += g * w_gate[c * E + t];
            s2 += g * w_noise[c * E + t];
        }
        float sp = fmaxf(s2, 0.f) + log1pf(expf(-fabsf(s2)));
        s_clean[t] = s1;
        s_std[t]   = sp + 0.01f;
        s_noisy[t] = s1 + noise[b * E + t] * (sp + 0.01f);
    }
    __syncthreads();
    if (t < E) {
        float m = s_noisy[0];
        #pragma unroll
        for (int e = 1; e < E; e++) m = fmaxf(m, s_noisy[e]);
        float den = 0.f;
        #pragma unroll
        for (int e = 0; e < E; e++) den += expf(s_noisy[e] - m);
        s_lg[t] = expf(s_noisy[t] - m) / den;
    }
    __syncthreads();
    // rank-based stable top-k (ties -> lower index first, matches top_k)
    if (t < E) {
        float v = s_lg[t]; int rank = 0;
        #pragma unroll
        for (int j = 0; j < E; j++) {
            float u = s_lg[j];
            rank += (u > v) || (u == v && j < t);
        }
        if (rank <= TOPK) s_tv[rank] = v;
        if (rank <  TOPK) s_gi[rank] = t;
    }
    __syncthreads();
    if (t < TOPK) {
        float s4 = s_tv[0] + s_tv[1] + s_tv[2] + s_tv[3] + 1e-6f;
        s_g[t] = s_tv[t] / s4;
    }
    __syncthreads();

    if (q == 0 && t < E) {
        float s4 = s_tv[0] + s_tv[1] + s_tv[2] + s_tv[3] + 1e-6f;
        float v = s_lg[t]; int rank = 0;
        #pragma unroll
        for (int j = 0; j < E; j++) {
            float u = s_lg[j];
            rank += (u > v) || (u == v && j < t);
        }
        gimpw[b * E + t] = (rank < TOPK) ? v / s4 : 0.f;
        const float INV_SQRT2 = 0.70710678118654752f;
        float thr_in = s_tv[TOPK], thr_out = s_tv[TOPK - 1];
        float thr = (s_noisy[t] > thr_in) ? thr_in : thr_out;
        float z = (s_clean[t] - thr) / s_std[t];
        probw[b * E + t] = 0.5f * (1.f + erff(z * INV_SQRT2));
    }
    if (q == 0 && t < COUT) {
        cbias[b * COUT + t] = s_g[0] * expert_b[s_gi[0] * 32 + t] + s_g[1] * expert_b[s_gi[1] * 32 + t]
                            + s_g[2] * expert_b[s_gi[2] * 32 + t] + s_g[3] * expert_b[s_gi[3] * 32 + t];
    }

    const float* e0 = expert_w + s_gi[0] * 9216;
    const float* e1 = expert_w + s_gi[1] * 9216;
    const float* e2 = expert_w + s_gi[2] * 9216;
    const float* e3 = expert_w + s_gi[3] * 9216;
    float g0 = s_g[0], g1 = s_g[1], g2 = s_g[2], g3 = s_g[3];
    // this quarter's 2304 outputs, output-major (dense cwb stores)
    #pragma unroll
    for (int k = 0; k < 9; k++) {
        int i = q * 2304 + k * 256 + t;     // = tap*1024 + cc
        int tap = i >> 10, cc = i & 1023;
        int rd = cc * 9 + tap;
        float s = g0 * e0[rd] + g1 * e1[rd] + g2 * e2[rd] + g3 * e3[rd];
        cwb[(size_t)b * 9216 + i] = f2bf(s);
    }
}

// ---------------------------------------------------------------------------
// Kernel 3: in-LDS transpose (R8's measured-best form) + MFMA conv + loss.
//   grid = B*16 swizzled, block 256 = 4 waves (one output row each).
//   afrag straight from L2-hot global cwb; no gating/combine in this kernel.
// ---------------------------------------------------------------------------
__global__ void __launch_bounds__(256)
conv_mfma(const float* __restrict__ x,
          const unsigned short* __restrict__ cwb,
          const float* __restrict__ cbias,
          const float* __restrict__ probw,
          const float* __restrict__ gimpw,
          float* __restrict__ y,
          float* __restrict__ loss_out) {
    int blk = swz1024(blockIdx.x);
    int b = blk >> 4, band = blk & 15, h0 = band << 2;
    int t = threadIdx.x, wave = t >> 6, l = t & 63;
    int ln = l & 15, lk = l >> 4;

    __shared__ unsigned short sx[6 * 66 * 32];   // x slab bf16, 25,344 B

    // ---- x slab: coalesced f32 reads, transposed bf16 LDS writes (R8) ----
    const float4* x4 = reinterpret_cast<const float4*>(x);
    #pragma unroll
    for (int k = 0; k < 12; k++) {
        int i = k * 256 + t;                // 0..3071
        int rr = i >> 9, c = (i >> 4) & 31, w4 = i & 15;
        int gr = h0 - 1 + rr;
        float4 v = {0.f, 0.f, 0.f, 0.f};
        if ((unsigned)gr < 64u)
            v = x4[(((size_t)(b * 32 + c) * 64 + gr) << 4) + w4];
        float vv[4] = {v.x, v.y, v.z, v.w};
        #pragma unroll
        for (int j = 0; j < 4; j++) {
            int wp = 1 + w4 * 4 + j;
            sx[(rr * 66 + wp) * 32 + cswz(wp, c)] = f2bf(vv[j]);
        }
    }
    // wp = 0 / 65 halo columns (cswz(0,c)=cswz(65,c)=c)
    for (int i = t; i < 384; i += 256) {
        int rr = i >> 6, rem = i & 63, side = rem >> 5, c = rem & 31;
        sx[(rr * 66 + side * 65) * 32 + c] = 0;
    }

    // ---- A-fragments + bias from global (L2-hot; overlaps with transpose) ----
    const unsigned short* wbase = cwb + (size_t)b * 9216;
    short8 afrag[2][9];
    #pragma unroll
    for (int tap = 0; tap < 9; tap++)
        #pragma unroll
        for (int ch = 0; ch < 2; ch++)
            afrag[ch][tap] = *reinterpret_cast<const short8*>(
                wbase + tap * 1024 + (ch * 16 + ln) * 32 + lk * 8);

    float bias0[4], bias1[4];
    #pragma unroll
    for (int r = 0; r < 4; r++) {
        bias0[r] = cbias[b * COUT + lk * 4 + r];
        bias1[r] = cbias[b * COUT + 16 + lk * 4 + r];
    }
    __syncthreads();

    // ---- MFMA conv: 9 shifted GEMMs, K=32 per mfma_f32_16x16x32_bf16 ----
    int h = h0 + wave;
    for (int tile = 0; tile < 4; tile++) {
        int w0 = tile * 16;
        f32x4 acc0 = {0.f, 0.f, 0.f, 0.f};
        f32x4 acc1 = {0.f, 0.f, 0.f, 0.f};
        #pragma unroll
        for (int kh = 0; kh < 3; kh++) {
            int rr = wave + kh;
            #pragma unroll
            for (int kw = 0; kw < 3; kw++) {
                int wp = w0 + ln + kw;
                short8 bfrag = *reinterpret_cast<const short8*>(
                    &sx[(rr * 66 + wp) * 32 + cswz(wp, lk * 8)]);
                acc0 = __builtin_amdgcn_mfma_f32_16x16x32_bf16(afrag[0][kh * 3 + kw], bfrag, acc0, 0, 0, 0);
                acc1 = __builtin_amdgcn_mfma_f32_16x16x32_bf16(afrag[1][kh * 3 + kw], bfrag, acc1, 0, 0, 0);
            }
        }
        #pragma unroll
        for (int r = 0; r < 4; r++) {
            y[((size_t)(b * COUT + lk * 4 + r) * 64 + h) * 64 + w0 + ln]      = acc0[r] + bias0[r];
            y[((size_t)(b * COUT + 16 + lk * 4 + r) * 64 + h) * 64 + w0 + ln] = acc1[r] + bias1[r];
        }
    }

    // ---- loss (logical block 0; inputs produced by gate_combine) ----
    if (blk == 0) {
        __shared__ float s_lv[32];
        if (t < 32) {
            const float* src = (t < 16) ? gimpw : probw;
            int e = t & 15;
            float s = 0.f;
            for (int bb = 0; bb < B; bb++) s += src[bb * E + e];
            s_lv[t] = s;
        }
        __syncthreads();
        if (t == 0) {
            float loss = 0.f;
            for (int pass = 0; pass < 2; pass++) {
                const float* v = s_lv + pass * 16;
                float mean = 0.f;
                for (int e = 0; e < E; e++) mean += v[e];
                mean *= (1.f / E);
                float var = 0.f;
                for (int e = 0; e < E; e++) { float d = v[e] - mean; var += d * d; }
                var *= (1.f / (E - 1));
                loss += var / (mean * mean + 1e-10f);
            }
            loss_out[0] = loss * 0.01f;
        }
    }
}

// ---------------------------------------------------------------------------
extern "C" void kernel_launch(void* const* d_in, const int* in_sizes, int n_in,
                              void* d_out, int out_size, void* d_ws, size_t ws_size,
                              hipStream_t stream) {
    const float* x        = (const float*)d_in[0];
    const float* noise    = (const float*)d_in[1];
    const float* w_gate   = (const float*)d_in[2];
    const float* w_noise  = (const float*)d_in[3];
    const float* expert_w = (const float*)d_in[4];
    const float* expert_b = (const float*)d_in[5];

    float* y    = (float*)d_out;
    float* loss = y + (size_t)B * COUT * 64 * 64;

    char* ws = (char*)d_ws;
    float*          bands  = (float*)(ws);             //   131,072 B
    float*          probw  = (float*)(ws + 131072);    //     4,096 B
    float*          gimpw  = (float*)(ws + 135168);    //     4,096 B
    float*          cbias  = (float*)(ws + 139264);    //     8,192 B
    unsigned short* cwb    = (unsigned short*)(ws + 147456); // 1,179,648 B

    bandsum_kernel<<<B * 16, 256, 0, stream>>>(x, bands);
    gate_combine<<<256, 256, 0, stream>>>(bands, noise, w_gate, w_noise,
                                          expert_w, expert_b, cwb, cbias,
                                          probw, gimpw);
    conv_mfma<<<B * 16, 256, 0, stream>>>(x, cwb, cbias, probw, gimpw, y, loss);
}